// Round 1
// baseline (412.926 us; speedup 1.0000x reference)
//
#include <hip/hip_runtime.h>
#include <hip/hip_bf16.h>

typedef _Float16 f16;
typedef _Float16 f16x4 __attribute__((ext_vector_type(4)));
typedef _Float16 f16x8 __attribute__((ext_vector_type(8)));
typedef float f32x4 __attribute__((ext_vector_type(4)));

#define B_  4
#define L_  2048
#define D_  4096
#define H_  8
#define BW_ 512
#define M_  (B_*L_)      // 8192
#define CHUNK 128
#define NCH (L_/CHUNK)   // 16

// workspace layout (bytes)
static const size_t OFF_WTIN  = 0;                        // H*BW*BW fp16 = 4MB (transposed: [h][j][i])
static const size_t OFF_WTA   = 4ull<<20;                 // 4MB
static const size_t OFF_MSP   = 8ull<<20;                 // D_ f32
static const size_t OFF_ABUF  = (8ull<<20) + (64ull<<10); // B*L*D f32 = 128MB
static const size_t OFF_SUMA  = OFF_ABUF + 134217728ull;  // B*NCH*D f32 = 1MB
static const size_t OFF_SUMY  = OFF_SUMA + (1ull<<20);
static const size_t OFF_CARRY = OFF_SUMY + (1ull<<20);

// ---------- prep: transpose+convert weights to fp16 [h][j][i] ----------
__global__ __launch_bounds__(256)
void prep_weights(const float* __restrict__ w_in, const float* __restrict__ w_a,
                  f16* __restrict__ wtin, f16* __restrict__ wta) {
    __shared__ float tile[32][33];
    int g = blockIdx.z >> 3;          // 0 = in, 1 = a
    int h = blockIdx.z & 7;
    const float* src = (g ? w_a : w_in) + (size_t)h * BW_ * BW_;
    f16* dst = (g ? wta : wtin) + (size_t)h * BW_ * BW_;
    int i0 = blockIdx.y * 32, j0 = blockIdx.x * 32;
    int tx = threadIdx.x & 31, ty = threadIdx.x >> 5;   // ty 0..7
#pragma unroll
    for (int q = 0; q < 4; ++q) {
        int i = ty + q * 8;
        tile[i][tx] = src[(size_t)(i0 + i) * BW_ + j0 + tx];
    }
    __syncthreads();
#pragma unroll
    for (int q = 0; q < 4; ++q) {
        int j = ty + q * 8;
        dst[(size_t)(j0 + j) * BW_ + i0 + tx] = (f16)tile[tx][j];
    }
}

// ---------- prep: msp[d] = -8 * softplus(a_param[d]) ----------
__global__ __launch_bounds__(256)
void prep_msp(const float* __restrict__ a_param, float* __restrict__ msp) {
    int d = blockIdx.x * 256 + threadIdx.x;
    float v = a_param[d];                 // values are negative; log1p(exp(v)) is stable
    msp[d] = -8.f * log1pf(expf(v));
}

// ---------- fused gate GEMM + epilogue ----------
// BM=128, BN=64, BK=64, 4 waves (2x2), wave tile 64x32, mfma 16x16x32 f16
#define BM 128
#define BN 64
#define BKK 64
#define LPAD 72   // fp16 units per LDS row (64 + 8 pad)

__global__ __launch_bounds__(256)
void gemm_gates(const float* __restrict__ x,
                const int*   __restrict__ segpos,
                const f16*   __restrict__ wtin,
                const f16*   __restrict__ wta,
                const float* __restrict__ b_in,
                const float* __restrict__ b_a,
                const float* __restrict__ msp,
                float* __restrict__ abuf,
                float* __restrict__ xnbuf /* = d_out */) {
    __shared__ f16 As [BM][LPAD];   // 18432 B
    __shared__ f16 Bsx[BN][LPAD];   //  9216 B
    __shared__ f16 Bsa[BN][LPAD];   //  9216 B

    const int tid  = threadIdx.x;
    const int m0   = blockIdx.x * BM;
    const int n0   = blockIdx.y * BN;
    const int h    = blockIdx.z;
    const int lane = tid & 63;
    const int wid  = tid >> 6;
    const int wr   = wid >> 1;   // 0..1  (row half)
    const int wc   = wid & 1;    // 0..1  (col half)

    f32x4 accX[4][2] = {};
    f32x4 accA[4][2] = {};

    // A staging map: 16 lanes cover one 64-f32 row (float4 each); 8 rows/thread
    const int a_c4 = (tid & 15) * 4;     // col within BK (f32 units)
    const int a_rb = tid >> 4;           // row base 0..15
    // B staging map: 8 lanes cover 64 fp16 of one row (8 fp16 each); 2 rows/thread
    const int b_k8 = (tid & 7) * 8;
    const int b_rb = tid >> 3;           // 0..31

    const float* xbase = x + (size_t)m0 * D_ + h * BW_;
    const f16* wxb = wtin + ((size_t)h * BW_ + n0) * BW_;
    const f16* wab = wta  + ((size_t)h * BW_ + n0) * BW_;

    for (int k0 = 0; k0 < BW_; k0 += BKK) {
        __syncthreads();   // protect previous iteration's LDS reads
        // stage A (f32 -> f16)
#pragma unroll
        for (int j = 0; j < 8; ++j) {
            int row = a_rb + 16 * j;
            f32x4 v = *(const f32x4*)(xbase + (size_t)row * D_ + k0 + a_c4);
            f16x4 hv = { (f16)v.x, (f16)v.y, (f16)v.z, (f16)v.w };
            *(f16x4*)&As[row][a_c4] = hv;
        }
        // stage B (both gates, already fp16, already transposed [n][k])
#pragma unroll
        for (int j = 0; j < 2; ++j) {
            int row = b_rb + 32 * j;
            *(f16x8*)&Bsx[row][b_k8] = *(const f16x8*)(wxb + (size_t)row * BW_ + k0 + b_k8);
            *(f16x8*)&Bsa[row][b_k8] = *(const f16x8*)(wab + (size_t)row * BW_ + k0 + b_k8);
        }
        __syncthreads();

#pragma unroll
        for (int kk = 0; kk < BKK; kk += 32) {
            const int kcol = kk + (lane >> 4) * 8;
            const int arow = wr * 64 + (lane & 15);
            f16x8 af[4];
#pragma unroll
            for (int fm = 0; fm < 4; ++fm)
                af[fm] = *(const f16x8*)&As[arow + fm * 16][kcol];
            const int brow = wc * 32 + (lane & 15);
#pragma unroll
            for (int fn = 0; fn < 2; ++fn) {
                f16x8 bx = *(const f16x8*)&Bsx[brow + fn * 16][kcol];
                f16x8 ba = *(const f16x8*)&Bsa[brow + fn * 16][kcol];
#pragma unroll
                for (int fm = 0; fm < 4; ++fm) {
                    accX[fm][fn] = __builtin_amdgcn_mfma_f32_16x16x32_f16(af[fm], bx, accX[fm][fn], 0, 0, 0);
                    accA[fm][fn] = __builtin_amdgcn_mfma_f32_16x16x32_f16(af[fm], ba, accA[fm][fn], 0, 0, 0);
                }
            }
        }
    }

    // epilogue: C/D layout col = lane&15, row = (lane>>4)*4 + reg  [m89-verified]
    const int colb = n0 + wc * 32 + (lane & 15);
    const int rowb = m0 + wr * 64 + ((lane >> 4) << 2);
#pragma unroll
    for (int fm = 0; fm < 4; ++fm) {
#pragma unroll
        for (int fn = 0; fn < 2; ++fn) {
            int j = colb + fn * 16;
            int d = h * BW_ + j;
            float bx = b_in[h * BW_ + j];
            float ba = b_a[h * BW_ + j];
            float mspd = msp[d];
#pragma unroll
            for (int reg = 0; reg < 4; ++reg) {
                int r = rowb + fm * 16 + reg;
                float gxl = accX[fm][fn][reg] + bx;
                float gal = accA[fm][fn][reg] + ba;
                float gx = 1.f / (1.f + expf(-gxl));
                float ga = 1.f / (1.f + expf(-gal));
                float la = mspd * ga;
                float a = expf(la);
                float mult = sqrtf(1.f - expf(2.f * la) + 1e-6f);
                if (segpos[r] == 0) { a = 0.f; mult = 1.f; }
                float xv = x[(size_t)r * D_ + d];
                size_t o = (size_t)r * D_ + d;
                abuf[o] = a;
                xnbuf[o] = xv * gx * mult;
            }
        }
    }
}

// ---------- scan phase 1: per-chunk summaries ----------
__global__ __launch_bounds__(256)
void scan_summary(const float* __restrict__ abuf, const float* __restrict__ xnbuf,
                  float* __restrict__ sumA, float* __restrict__ sumY) {
    int d = blockIdx.x * 256 + threadIdx.x;
    int c = blockIdx.y, b = blockIdx.z;
    size_t base = ((size_t)(b * L_ + c * CHUNK)) * D_ + d;
    float A = 1.f, yv = 0.f;
#pragma unroll 4
    for (int t = 0; t < CHUNK; ++t) {
        float a  = abuf[base + (size_t)t * D_];
        float xn = xnbuf[base + (size_t)t * D_];
        yv = fmaf(a, yv, xn);
        A *= a;
    }
    size_t si = ((size_t)b * NCH + c) * D_ + d;
    sumA[si] = A;
    sumY[si] = yv;
}

// ---------- scan phase 2: scan over chunk summaries -> carry-in per chunk ----------
__global__ __launch_bounds__(256)
void scan_mid(const float* __restrict__ sumA, const float* __restrict__ sumY,
              float* __restrict__ carry) {
    int d = blockIdx.x * 256 + threadIdx.x;
    int b = blockIdx.y;
    float hcur = 0.f;
#pragma unroll
    for (int c = 0; c < NCH; ++c) {
        size_t si = ((size_t)b * NCH + c) * D_ + d;
        carry[si] = hcur;
        hcur = fmaf(sumA[si], hcur, sumY[si]);
    }
}

// ---------- scan phase 3: apply (in-place on d_out) ----------
__global__ __launch_bounds__(256)
void scan_apply(const float* __restrict__ abuf, const float* __restrict__ carry,
                float* __restrict__ y) {
    int d = blockIdx.x * 256 + threadIdx.x;
    int c = blockIdx.y, b = blockIdx.z;
    size_t si = ((size_t)b * NCH + c) * D_ + d;
    float hv = carry[si];
    size_t base = ((size_t)(b * L_ + c * CHUNK)) * D_ + d;
#pragma unroll 4
    for (int t = 0; t < CHUNK; ++t) {
        float a  = abuf[base + (size_t)t * D_];
        float xn = y[base + (size_t)t * D_];
        hv = fmaf(a, hv, xn);
        y[base + (size_t)t * D_] = hv;
    }
}

extern "C" void kernel_launch(void* const* d_in, const int* in_sizes, int n_in,
                              void* d_out, int out_size, void* d_ws, size_t ws_size,
                              hipStream_t stream) {
    const float* x       = (const float*)d_in[0];
    const int*   segpos  = (const int*)d_in[1];
    // d_in[2] = prev_h (unused by reference for L>1 path)
    const float* w_in    = (const float*)d_in[3];
    const float* b_in    = (const float*)d_in[4];
    const float* w_a     = (const float*)d_in[5];
    const float* b_a     = (const float*)d_in[6];
    const float* a_param = (const float*)d_in[7];

    float* y  = (float*)d_out;
    char*  ws = (char*)d_ws;
    f16*   wtin  = (f16*)(ws + OFF_WTIN);
    f16*   wta   = (f16*)(ws + OFF_WTA);
    float* msp   = (float*)(ws + OFF_MSP);
    float* abuf  = (float*)(ws + OFF_ABUF);
    float* sumA  = (float*)(ws + OFF_SUMA);
    float* sumY  = (float*)(ws + OFF_SUMY);
    float* carry = (float*)(ws + OFF_CARRY);

    prep_weights<<<dim3(16, 16, 16), 256, 0, stream>>>(w_in, w_a, wtin, wta);
    prep_msp<<<dim3(D_ / 256), 256, 0, stream>>>(a_param, msp);
    gemm_gates<<<dim3(M_ / BM, BW_ / BN, H_), 256, 0, stream>>>(
        x, segpos, wtin, wta, b_in, b_a, msp, abuf, y);
    scan_summary<<<dim3(D_ / 256, NCH, B_), 256, 0, stream>>>(abuf, y, sumA, sumY);
    scan_mid<<<dim3(D_ / 256, B_), 256, 0, stream>>>(sumA, sumY, carry);
    scan_apply<<<dim3(D_ / 256, NCH, B_), 256, 0, stream>>>(abuf, carry, y);
}

// Round 2
// 363.502 us; speedup vs baseline: 1.1360x; 1.1360x over previous
//
#include <hip/hip_runtime.h>
#include <hip/hip_bf16.h>

typedef _Float16 f16;
typedef _Float16 f16x4 __attribute__((ext_vector_type(4)));
typedef _Float16 f16x8 __attribute__((ext_vector_type(8)));
typedef float f32x4 __attribute__((ext_vector_type(4)));

#define B_  4
#define L_  2048
#define D_  4096
#define H_  8
#define BW_ 512
#define M_  (B_*L_)      // 8192
#define CHUNK 128
#define NCH (L_/CHUNK)   // 16

// workspace layout (bytes)
static const size_t OFF_WTIN  = 0;                 // H*BW*BW fp16 = 4MB, transposed [h][n][k]
static const size_t OFF_WTA   = 4ull<<20;          // 4MB
static const size_t OFF_MSP   = 8ull<<20;          // D_ f32 (16KB)
static const size_t OFF_XH    = 9ull<<20;          // M*D fp16 = 64MB
static const size_t OFF_APFX  = 73ull<<20;         // M*D fp16 = 64MB
static const size_t OFF_SUMA  = 137ull<<20;        // B*NCH*D f32 = 1MB
static const size_t OFF_SUMY  = 138ull<<20;
static const size_t OFF_CARRY = 139ull<<20;

__device__ __forceinline__ void gl16(const void* g, void* l) {
    __builtin_amdgcn_global_load_lds(
        (const __attribute__((address_space(1))) unsigned int*)g,
        (__attribute__((address_space(3))) unsigned int*)l, 16, 0, 0);
}

// ---------- prep: transpose+convert weights to fp16 [h][n][k] ----------
__global__ __launch_bounds__(256)
void prep_weights(const float* __restrict__ w_in, const float* __restrict__ w_a,
                  f16* __restrict__ wtin, f16* __restrict__ wta) {
    __shared__ float tile[32][33];
    int g = blockIdx.z >> 3;          // 0 = in, 1 = a
    int h = blockIdx.z & 7;
    const float* src = (g ? w_a : w_in) + (size_t)h * BW_ * BW_;
    f16* dst = (g ? wta : wtin) + (size_t)h * BW_ * BW_;
    int i0 = blockIdx.y * 32, j0 = blockIdx.x * 32;
    int tx = threadIdx.x & 31, ty = threadIdx.x >> 5;
#pragma unroll
    for (int q = 0; q < 4; ++q) {
        int i = ty + q * 8;
        tile[i][tx] = src[(size_t)(i0 + i) * BW_ + j0 + tx];
    }
    __syncthreads();
#pragma unroll
    for (int q = 0; q < 4; ++q) {
        int j = ty + q * 8;
        dst[(size_t)(j0 + j) * BW_ + i0 + tx] = (f16)tile[tx][j];
    }
}

// ---------- prep: msp[d] = -8 * softplus(a_param[d]) ----------
__global__ __launch_bounds__(256)
void prep_msp(const float* __restrict__ a_param, float* __restrict__ msp) {
    int d = blockIdx.x * 256 + threadIdx.x;
    float v = a_param[d];
    msp[d] = -8.f * log1pf(expf(v));
}

// ---------- prep: x -> fp16 ----------
__global__ __launch_bounds__(256)
void prep_xh(const float* __restrict__ x, f16* __restrict__ xh) {
    size_t i = ((size_t)blockIdx.x * 256 + threadIdx.x) * 8;
    size_t stride = (size_t)gridDim.x * 256 * 8;
    for (; i < (size_t)M_ * D_; i += stride) {
        f32x4 v0 = *(const f32x4*)(x + i);
        f32x4 v1 = *(const f32x4*)(x + i + 4);
        f16x8 hv;
        hv[0] = (f16)v0.x; hv[1] = (f16)v0.y; hv[2] = (f16)v0.z; hv[3] = (f16)v0.w;
        hv[4] = (f16)v1.x; hv[5] = (f16)v1.y; hv[6] = (f16)v1.z; hv[7] = (f16)v1.w;
        *(f16x8*)(xh + i) = hv;
    }
}

// ---------- fused gate GEMM + epilogue + chunk-local scan ----------
// BM=128 (= one scan chunk), BN=64, BK=64, 4 waves (2x2), mfma 16x16x32 f16
#define BM 128
#define BN 64
#define BKK 64

// LDS overlay (bytes):
//  staging: As[128][64]f16=16384 | Bsx[64][64]f16=8192 | Bsa=8192  -> 32768
//  scan:    a_s[128][65]f32=33280 | xn_s[128][66]f16=16896 |
//           segA[4][72]f32=1152 | segY[4][72]f32=1152        -> 52480
#define SMEM_BYTES 52480

__global__ __launch_bounds__(256)
void gemm_gates(const f16*   __restrict__ xh,
                const int*   __restrict__ segpos,
                const f16*   __restrict__ wtin,
                const f16*   __restrict__ wta,
                const float* __restrict__ b_in,
                const float* __restrict__ b_a,
                const float* __restrict__ msp,
                f16*   __restrict__ apfx,
                float* __restrict__ sumA,
                float* __restrict__ sumY,
                float* __restrict__ yloc /* = d_out */) {
    __shared__ __align__(16) char smem[SMEM_BYTES];
    f16*   As   = (f16*)smem;                 // [128][64]
    f16*   Bsx  = (f16*)(smem + 16384);       // [64][64]
    f16*   Bsa  = (f16*)(smem + 24576);       // [64][64]
    float* a_s  = (float*)smem;               // [128][65]
    f16*   xn_s = (f16*)(smem + 33280);       // [128][66]
    float* segA = (float*)(smem + 50176);     // [4][72]
    float* segY = (float*)(smem + 51328);     // [4][72]

    const int tid  = threadIdx.x;
    const int m0   = blockIdx.x * BM;
    const int n0   = blockIdx.y * BN;
    const int h    = blockIdx.z;
    const int lane = tid & 63;
    const int wid  = tid >> 6;
    const int wr   = wid >> 1;
    const int wc   = wid & 1;

    f32x4 accX[4][2] = {};
    f32x4 accA[4][2] = {};

    const f16* xbase = xh + (size_t)m0 * D_ + h * BW_;
    const f16* wxb = wtin + ((size_t)h * BW_ + n0) * BW_;
    const f16* wab = wta  + ((size_t)h * BW_ + n0) * BW_;

    const int grow = lane >> 3;       // 0..7 row-within-8 for gload
    const int gcol = (lane & 7) * 8;  // f16 col for gload

    for (int k0 = 0; k0 < BW_; k0 += BKK) {
        __syncthreads();   // previous tile's reads done
        // A tile: 16KB, 4 instr/wave (8 rows each)
#pragma unroll
        for (int q = 0; q < 4; ++q) {
            int rb = wid * 32 + q * 8;
            gl16(xbase + (size_t)(rb + grow) * D_ + k0 + gcol, &As[rb * 64]);
        }
        // B tiles: 8KB each, 2 instr/wave/gate
#pragma unroll
        for (int q = 0; q < 2; ++q) {
            int rb = wid * 16 + q * 8;
            gl16(wxb + (size_t)(rb + grow) * BW_ + k0 + gcol, &Bsx[rb * 64]);
            gl16(wab + (size_t)(rb + grow) * BW_ + k0 + gcol, &Bsa[rb * 64]);
        }
        __syncthreads();   // compiler drains vmcnt(0) here

#pragma unroll
        for (int kk = 0; kk < BKK; kk += 32) {
            const int kcol = kk + (lane >> 4) * 8;
            const int arow = wr * 64 + (lane & 15);
            f16x8 af[4];
#pragma unroll
            for (int fm = 0; fm < 4; ++fm)
                af[fm] = *(const f16x8*)&As[(arow + fm * 16) * 64 + kcol];
            const int brow = wc * 32 + (lane & 15);
#pragma unroll
            for (int fn = 0; fn < 2; ++fn) {
                f16x8 bx = *(const f16x8*)&Bsx[(brow + fn * 16) * 64 + kcol];
                f16x8 ba = *(const f16x8*)&Bsa[(brow + fn * 16) * 64 + kcol];
#pragma unroll
                for (int fm = 0; fm < 4; ++fm) {
                    accX[fm][fn] = __builtin_amdgcn_mfma_f32_16x16x32_f16(af[fm], bx, accX[fm][fn], 0, 0, 0);
                    accA[fm][fn] = __builtin_amdgcn_mfma_f32_16x16x32_f16(af[fm], ba, accA[fm][fn], 0, 0, 0);
                }
            }
        }
    }

    __syncthreads();   // all MFMA LDS reads done before overlay write

    // ---- pass A: epilogue math, deposit a (f32) + xn (f16) into LDS ----
    // C/D layout: col = lane&15, row = (lane>>4)*4 + reg  [m89-verified]
    {
        const int rowb = wr * 64 + ((lane >> 4) << 2);
#pragma unroll
        for (int fn = 0; fn < 2; ++fn) {
            const int ctile = wc * 32 + fn * 16 + (lane & 15);
            const int j = n0 + ctile;
            const int d = h * BW_ + j;
            const float bx = b_in[d];
            const float ba = b_a[d];
            const float mspd = msp[d];
#pragma unroll
            for (int fm = 0; fm < 4; ++fm) {
#pragma unroll
                for (int reg = 0; reg < 4; ++reg) {
                    const int rowt = rowb + fm * 16 + reg;       // 0..127
                    const int r = m0 + rowt;
                    float gxl = accX[fm][fn][reg] + bx;
                    float gal = accA[fm][fn][reg] + ba;
                    float gx = 1.f / (1.f + expf(-gxl));
                    float ga = 1.f / (1.f + expf(-gal));
                    float la = mspd * ga;
                    float a = expf(la);
                    float mult = sqrtf(1.f - expf(2.f * la) + 1e-6f);
                    if (segpos[r] == 0) { a = 0.f; mult = 1.f; }
                    float xv = (float)xh[(size_t)r * D_ + d];
                    a_s[rowt * 65 + ctile] = a;
                    xn_s[rowt * 66 + ctile] = (f16)(xv * gx * mult);
                }
            }
        }
    }
    __syncthreads();

    // ---- pass B: per-segment (32-step) summaries ----
    const int scol = tid & 63;
    const int sseg = tid >> 6;
    {
        float A = 1.f, yv = 0.f;
#pragma unroll 4
        for (int t = sseg * 32; t < sseg * 32 + 32; ++t) {
            float a  = a_s[t * 65 + scol];
            float xn = (float)xn_s[t * 66 + scol];
            yv = fmaf(a, yv, xn);
            A *= a;
        }
        segA[sseg * 72 + scol] = A;
        segY[sseg * 72 + scol] = yv;
    }
    __syncthreads();

    // ---- pass C: carry-in per segment, rewalk, write ylocal + Apfx ----
    {
        float cy = 0.f, pA = 1.f;
        for (int s = 0; s < sseg; ++s) {
            float As_ = segA[s * 72 + scol];
            float Ys_ = segY[s * 72 + scol];
            cy = fmaf(As_, cy, Ys_);
            pA *= As_;
        }
        float Arun = 1.f, yv = cy;
        const size_t obase = (size_t)(m0 + sseg * 32) * D_ + h * BW_ + n0 + scol;
#pragma unroll 4
        for (int i = 0; i < 32; ++i) {
            const int t = sseg * 32 + i;
            float a  = a_s[t * 65 + scol];
            float xn = (float)xn_s[t * 66 + scol];
            yv = fmaf(a, yv, xn);
            Arun *= a;
            size_t o = obase + (size_t)i * D_;
            yloc[o] = yv;
            apfx[o] = (f16)(pA * Arun);
        }
        if (sseg == 3) {
            const int bb = m0 >> 11;             // batch
            const int cc = (m0 & 2047) >> 7;     // chunk in batch
            size_t si = ((size_t)bb * NCH + cc) * D_ + h * BW_ + n0 + scol;
            sumA[si] = pA * Arun;
            sumY[si] = yv;
        }
    }
}

// ---------- scan phase 2: scan over chunk summaries -> carry-in per chunk ----------
__global__ __launch_bounds__(256)
void scan_mid(const float* __restrict__ sumA, const float* __restrict__ sumY,
              float* __restrict__ carry) {
    int d = blockIdx.x * 256 + threadIdx.x;
    int b = blockIdx.y;
    float hcur = 0.f;
#pragma unroll
    for (int c = 0; c < NCH; ++c) {
        size_t si = ((size_t)b * NCH + c) * D_ + d;
        carry[si] = hcur;
        hcur = fmaf(sumA[si], hcur, sumY[si]);
    }
}

// ---------- scan phase 3: elementwise apply y = ylocal + carry * Apfx ----------
__global__ __launch_bounds__(256)
void scan_apply(const float* __restrict__ carry, const f16* __restrict__ apfx,
                float* __restrict__ y) {
    size_t i4 = (size_t)blockIdx.x * 256 + threadIdx.x;
    const size_t stride = (size_t)gridDim.x * 256;
    const size_t n4 = (size_t)M_ * D_ / 4;
    for (; i4 < n4; i4 += stride) {
        size_t i = i4 * 4;
        size_t row = i >> 12;
        int d = (int)(i & 4095);
        int b = (int)(row >> 11);
        int c = ((int)row & 2047) >> 7;
        const float* cp = carry + (((size_t)(b * NCH + c)) << 12) + d;
        f32x4 yv = *(const f32x4*)(y + i);
        f16x4 ap = *(const f16x4*)(apfx + i);
        f32x4 cv = *(const f32x4*)cp;
        yv.x = fmaf(cv.x, (float)ap[0], yv.x);
        yv.y = fmaf(cv.y, (float)ap[1], yv.y);
        yv.z = fmaf(cv.z, (float)ap[2], yv.z);
        yv.w = fmaf(cv.w, (float)ap[3], yv.w);
        *(f32x4*)(y + i) = yv;
    }
}

extern "C" void kernel_launch(void* const* d_in, const int* in_sizes, int n_in,
                              void* d_out, int out_size, void* d_ws, size_t ws_size,
                              hipStream_t stream) {
    const float* x       = (const float*)d_in[0];
    const int*   segpos  = (const int*)d_in[1];
    // d_in[2] = prev_h (unused by reference for L>1 path)
    const float* w_in    = (const float*)d_in[3];
    const float* b_in    = (const float*)d_in[4];
    const float* w_a     = (const float*)d_in[5];
    const float* b_a     = (const float*)d_in[6];
    const float* a_param = (const float*)d_in[7];

    float* y  = (float*)d_out;
    char*  ws = (char*)d_ws;
    f16*   wtin  = (f16*)(ws + OFF_WTIN);
    f16*   wta   = (f16*)(ws + OFF_WTA);
    float* msp   = (float*)(ws + OFF_MSP);
    f16*   xh    = (f16*)(ws + OFF_XH);
    f16*   apfx  = (f16*)(ws + OFF_APFX);
    float* sumA  = (float*)(ws + OFF_SUMA);
    float* sumY  = (float*)(ws + OFF_SUMY);
    float* carry = (float*)(ws + OFF_CARRY);

    prep_weights<<<dim3(16, 16, 16), 256, 0, stream>>>(w_in, w_a, wtin, wta);
    prep_msp<<<dim3(D_ / 256), 256, 0, stream>>>(a_param, msp);
    prep_xh<<<dim3(2048), 256, 0, stream>>>(x, xh);
    gemm_gates<<<dim3(M_ / BM, BW_ / BN, H_), 256, 0, stream>>>(
        xh, segpos, wtin, wta, b_in, b_a, msp, apfx, sumA, sumY, y);
    scan_mid<<<dim3(D_ / 256, B_), 256, 0, stream>>>(sumA, sumY, carry);
    scan_apply<<<dim3(4096), 256, 0, stream>>>(carry, apfx, y);
}

// Round 3
// 284.153 us; speedup vs baseline: 1.4532x; 1.2792x over previous
//
#include <hip/hip_runtime.h>
#include <hip/hip_bf16.h>

typedef _Float16 f16;
typedef _Float16 f16x4 __attribute__((ext_vector_type(4)));
typedef _Float16 f16x8 __attribute__((ext_vector_type(8)));
typedef float f32x4 __attribute__((ext_vector_type(4)));

#define B_  4
#define L_  2048
#define D_  4096
#define H_  8
#define BW_ 512
#define M_  (B_*L_)      // 8192
#define CHUNK 128
#define NCH (L_/CHUNK)   // 16
#define LOG2E 1.4426950408889634f

// workspace layout (bytes)
static const size_t OFF_WTIN  = 0;                 // H*BW*BW fp16 = 4MB, transposed [h][n][k]
static const size_t OFF_WTA   = 4ull<<20;          // 4MB
static const size_t OFF_MSP   = 8ull<<20;          // D_ f32 (16KB)  (pre-scaled by log2e)
static const size_t OFF_XH    = 9ull<<20;          // M*D fp16 = 64MB
static const size_t OFF_APFX  = 73ull<<20;         // M*D fp16 = 64MB
static const size_t OFF_SUMA  = 137ull<<20;        // B*NCH*D f32 = 1MB
static const size_t OFF_SUMY  = 138ull<<20;
static const size_t OFF_CARRY = 139ull<<20;

__device__ __forceinline__ void gl16(const void* g, void* l) {
    __builtin_amdgcn_global_load_lds(
        (const __attribute__((address_space(1))) unsigned int*)g,
        (__attribute__((address_space(3))) unsigned int*)l, 16, 0, 0);
}

// ---------- prep: transpose+convert weights to fp16 [h][n][k] ----------
__global__ __launch_bounds__(256)
void prep_weights(const float* __restrict__ w_in, const float* __restrict__ w_a,
                  f16* __restrict__ wtin, f16* __restrict__ wta) {
    __shared__ float tile[32][33];
    int g = blockIdx.z >> 3;          // 0 = in, 1 = a
    int h = blockIdx.z & 7;
    const float* src = (g ? w_a : w_in) + (size_t)h * BW_ * BW_;
    f16* dst = (g ? wta : wtin) + (size_t)h * BW_ * BW_;
    int i0 = blockIdx.y * 32, j0 = blockIdx.x * 32;
    int tx = threadIdx.x & 31, ty = threadIdx.x >> 5;
#pragma unroll
    for (int q = 0; q < 4; ++q) {
        int i = ty + q * 8;
        tile[i][tx] = src[(size_t)(i0 + i) * BW_ + j0 + tx];
    }
    __syncthreads();
#pragma unroll
    for (int q = 0; q < 4; ++q) {
        int j = ty + q * 8;
        dst[(size_t)(j0 + j) * BW_ + i0 + tx] = (f16)tile[tx][j];
    }
}

// ---------- prep: msp2[d] = -8 * softplus(a_param[d]) * log2(e) ----------
__global__ __launch_bounds__(256)
void prep_msp(const float* __restrict__ a_param, float* __restrict__ msp2) {
    int d = blockIdx.x * 256 + threadIdx.x;
    float v = a_param[d];
    msp2[d] = -8.f * log1pf(expf(v)) * LOG2E;
}

// ---------- prep: x -> fp16 ----------
__global__ __launch_bounds__(256)
void prep_xh(const float* __restrict__ x, f16* __restrict__ xh) {
    size_t i = ((size_t)blockIdx.x * 256 + threadIdx.x) * 8;
    size_t stride = (size_t)gridDim.x * 256 * 8;
    for (; i < (size_t)M_ * D_; i += stride) {
        f32x4 v0 = *(const f32x4*)(x + i);
        f32x4 v1 = *(const f32x4*)(x + i + 4);
        f16x8 hv;
        hv[0] = (f16)v0.x; hv[1] = (f16)v0.y; hv[2] = (f16)v0.z; hv[3] = (f16)v0.w;
        hv[4] = (f16)v1.x; hv[5] = (f16)v1.y; hv[6] = (f16)v1.z; hv[7] = (f16)v1.w;
        *(f16x8*)(xh + i) = hv;
    }
}

// ---------- fused gate GEMM + epilogue + chunk-local scan ----------
// BM=128 (= one scan chunk), BN=64, BK=64, 4 waves (2x2), mfma 16x16x32 f16
#define BM 128
#define BN 64
#define BKK 64

// LDS overlay (bytes):
//  staging: As[128][64]f16=16384 | Bsx[64][64]f16=8192 | Bsa=8192  -> 32768
//  scan:    a_s[128][65]f32=33280 | xn_s[128][66]f16=16896 |
//           segA[4][72]f32=1152 | segY[4][72]f32=1152 | rst[128]f32=512 -> 52992
#define SMEM_BYTES 52992

__global__ __launch_bounds__(256)
void gemm_gates(const f16*   __restrict__ xh,
                const int*   __restrict__ segpos,
                const f16*   __restrict__ wtin,
                const f16*   __restrict__ wta,
                const float* __restrict__ b_in,
                const float* __restrict__ b_a,
                const float* __restrict__ msp2,
                f16*   __restrict__ apfx,
                float* __restrict__ sumA,
                float* __restrict__ sumY,
                float* __restrict__ yloc /* = d_out */) {
    __shared__ __align__(16) char smem[SMEM_BYTES];
    f16*   As   = (f16*)smem;                 // [128][64] (col-swizzled physical)
    f16*   Bsx  = (f16*)(smem + 16384);       // [64][64]
    f16*   Bsa  = (f16*)(smem + 24576);       // [64][64]
    float* a_s  = (float*)smem;               // [128][65]
    f16*   xn_s = (f16*)(smem + 33280);       // [128][66]
    float* segA = (float*)(smem + 50176);     // [4][72]
    float* segY = (float*)(smem + 51328);     // [4][72]
    float* rst_s= (float*)(smem + 52480);     // [128]

    const int tid  = threadIdx.x;
    const int m0   = blockIdx.x * BM;
    const int n0   = blockIdx.y * BN;
    const int h    = blockIdx.z;
    const int lane = tid & 63;
    const int wid  = tid >> 6;
    const int wr   = wid >> 1;
    const int wc   = wid & 1;

    f32x4 accX[4][2] = {};
    f32x4 accA[4][2] = {};

    // reset flags -> LDS (outside staging overlay; covered by first barrier)
    if (tid < BM) rst_s[tid] = (segpos[m0 + tid] == 0) ? 1.f : 0.f;

    // staging maps: lane covers (row = base + lane>>3, physical col (lane&7)*8)
    // physical col pc holds logical col pc ^ ((row&7)<<3); row bases are mult-of-8
    // so the source column is gcolS = ((lane&7) ^ (lane>>3)) * 8  (m173/m201 pattern)
    const int grow  = lane >> 3;
    const int gcolS = (((lane & 7) ^ grow) << 3);
    const f16* aSrc  = xh   + (size_t)(m0 + wid * 32 + grow) * D_ + h * BW_ + gcolS;
    const f16* bxSrc = wtin + ((size_t)h * BW_ + n0 + wid * 16 + grow) * BW_ + gcolS;
    const f16* baSrc = wta  + ((size_t)h * BW_ + n0 + wid * 16 + grow) * BW_ + gcolS;

    const int swz  = (lane & 7) << 3;        // read-side XOR (involution)
    const int kx   = (lane >> 4) << 3;       // 0,8,16,24
    const int arow = wr * 64 + (lane & 15);
    const int brow = wc * 32 + (lane & 15);

    for (int k0 = 0; k0 < BW_; k0 += BKK) {
        __syncthreads();   // previous tile's reads done
#pragma unroll
        for (int q = 0; q < 4; ++q)
            gl16(aSrc + k0 + (size_t)q * 8 * D_, &As[(wid * 32 + q * 8) * 64]);
#pragma unroll
        for (int q = 0; q < 2; ++q) {
            gl16(bxSrc + k0 + (size_t)q * 8 * BW_, &Bsx[(wid * 16 + q * 8) * 64]);
            gl16(baSrc + k0 + (size_t)q * 8 * BW_, &Bsa[(wid * 16 + q * 8) * 64]);
        }
        __syncthreads();   // compiler drains vmcnt(0) here

#pragma unroll
        for (int kk = 0; kk < BKK; kk += 32) {
            const int kcolS = (kk + kx) ^ swz;
            f16x8 af[4];
#pragma unroll
            for (int fm = 0; fm < 4; ++fm)
                af[fm] = *(const f16x8*)&As[(arow + fm * 16) * 64 + kcolS];
#pragma unroll
            for (int fn = 0; fn < 2; ++fn) {
                f16x8 bx = *(const f16x8*)&Bsx[(brow + fn * 16) * 64 + kcolS];
                f16x8 ba = *(const f16x8*)&Bsa[(brow + fn * 16) * 64 + kcolS];
#pragma unroll
                for (int fm = 0; fm < 4; ++fm) {
                    accX[fm][fn] = __builtin_amdgcn_mfma_f32_16x16x32_f16(af[fm], bx, accX[fm][fn], 0, 0, 0);
                    accA[fm][fn] = __builtin_amdgcn_mfma_f32_16x16x32_f16(af[fm], ba, accA[fm][fn], 0, 0, 0);
                }
            }
        }
    }

    __syncthreads();   // all MFMA LDS reads done before overlay write

    // ---- pass A: epilogue math, deposit a (f32) + xn (f16) into LDS ----
    // C/D layout: col = lane&15, row = (lane>>4)*4 + reg  [m89-verified]
    {
        const int rowb = wr * 64 + ((lane >> 4) << 2);
#pragma unroll
        for (int fn = 0; fn < 2; ++fn) {
            const int ctile = wc * 32 + fn * 16 + (lane & 15);
            const int j = n0 + ctile;
            const int d = h * BW_ + j;
            const float bx = b_in[d];
            const float ba = b_a[d];
            const float mspd = msp2[d];
#pragma unroll
            for (int fm = 0; fm < 4; ++fm) {
#pragma unroll
                for (int reg = 0; reg < 4; ++reg) {
                    const int rowt = rowb + fm * 16 + reg;       // 0..127
                    const int r = m0 + rowt;
                    float gxl = accX[fm][fn][reg] + bx;
                    float gal = accA[fm][fn][reg] + ba;
                    float gx = __builtin_amdgcn_rcpf(1.f + __builtin_amdgcn_exp2f(-gxl * LOG2E));
                    float ga = __builtin_amdgcn_rcpf(1.f + __builtin_amdgcn_exp2f(-gal * LOG2E));
                    float a  = __builtin_amdgcn_exp2f(mspd * ga);
                    float a2 = a * a;                            // = exp(2*log_a)
                    float mult = __builtin_amdgcn_sqrtf(1.f + 1e-6f - a2);
                    float rv = rst_s[rowt];
                    a *= (1.f - rv);
                    mult = rv + (1.f - rv) * mult;
                    float xv = (float)xh[(size_t)r * D_ + d];
                    a_s[rowt * 65 + ctile] = a;
                    xn_s[rowt * 66 + ctile] = (f16)(xv * gx * mult);
                }
            }
        }
    }
    __syncthreads();

    // ---- pass B: per-segment (32-step) summaries ----
    const int scol = tid & 63;
    const int sseg = tid >> 6;
    {
        float A = 1.f, yv = 0.f;
#pragma unroll 4
        for (int t = sseg * 32; t < sseg * 32 + 32; ++t) {
            float a  = a_s[t * 65 + scol];
            float xn = (float)xn_s[t * 66 + scol];
            yv = fmaf(a, yv, xn);
            A *= a;
        }
        segA[sseg * 72 + scol] = A;
        segY[sseg * 72 + scol] = yv;
    }
    __syncthreads();

    // ---- pass C: carry-in per segment, rewalk, write ylocal + Apfx ----
    {
        float cy = 0.f, pA = 1.f;
        for (int s = 0; s < sseg; ++s) {
            float As_ = segA[s * 72 + scol];
            float Ys_ = segY[s * 72 + scol];
            cy = fmaf(As_, cy, Ys_);
            pA *= As_;
        }
        float Arun = 1.f, yv = cy;
        const size_t obase = (size_t)(m0 + sseg * 32) * D_ + h * BW_ + n0 + scol;
#pragma unroll 4
        for (int i = 0; i < 32; ++i) {
            const int t = sseg * 32 + i;
            float a  = a_s[t * 65 + scol];
            float xn = (float)xn_s[t * 66 + scol];
            yv = fmaf(a, yv, xn);
            Arun *= a;
            size_t o = obase + (size_t)i * D_;
            yloc[o] = yv;
            apfx[o] = (f16)(pA * Arun);
        }
        if (sseg == 3) {
            const int bb = m0 >> 11;             // batch
            const int cc = (m0 & 2047) >> 7;     // chunk in batch
            size_t si = ((size_t)bb * NCH + cc) * D_ + h * BW_ + n0 + scol;
            sumA[si] = pA * Arun;
            sumY[si] = yv;
        }
    }
}

// ---------- scan phase 2: scan over chunk summaries -> carry-in per chunk ----------
__global__ __launch_bounds__(256)
void scan_mid(const float* __restrict__ sumA, const float* __restrict__ sumY,
              float* __restrict__ carry) {
    int d = blockIdx.x * 256 + threadIdx.x;
    int b = blockIdx.y;
    float hcur = 0.f;
#pragma unroll
    for (int c = 0; c < NCH; ++c) {
        size_t si = ((size_t)b * NCH + c) * D_ + d;
        carry[si] = hcur;
        hcur = fmaf(sumA[si], hcur, sumY[si]);
    }
}

// ---------- scan phase 3: elementwise apply y = ylocal + carry * Apfx ----------
__global__ __launch_bounds__(256)
void scan_apply(const float* __restrict__ carry, const f16* __restrict__ apfx,
                float* __restrict__ y) {
    size_t i4 = (size_t)blockIdx.x * 256 + threadIdx.x;
    const size_t stride = (size_t)gridDim.x * 256;
    const size_t n4 = (size_t)M_ * D_ / 4;
    for (; i4 < n4; i4 += stride) {
        size_t i = i4 * 4;
        size_t row = i >> 12;
        int d = (int)(i & 4095);
        int b = (int)(row >> 11);
        int c = ((int)row & 2047) >> 7;
        const float* cp = carry + (((size_t)(b * NCH + c)) << 12) + d;
        f32x4 yv = *(const f32x4*)(y + i);
        f16x4 ap = *(const f16x4*)(apfx + i);
        f32x4 cv = *(const f32x4*)cp;
        yv.x = fmaf(cv.x, (float)ap[0], yv.x);
        yv.y = fmaf(cv.y, (float)ap[1], yv.y);
        yv.z = fmaf(cv.z, (float)ap[2], yv.z);
        yv.w = fmaf(cv.w, (float)ap[3], yv.w);
        *(f32x4*)(y + i) = yv;
    }
}

extern "C" void kernel_launch(void* const* d_in, const int* in_sizes, int n_in,
                              void* d_out, int out_size, void* d_ws, size_t ws_size,
                              hipStream_t stream) {
    const float* x       = (const float*)d_in[0];
    const int*   segpos  = (const int*)d_in[1];
    // d_in[2] = prev_h (unused by reference for L>1 path)
    const float* w_in    = (const float*)d_in[3];
    const float* b_in    = (const float*)d_in[4];
    const float* w_a     = (const float*)d_in[5];
    const float* b_a     = (const float*)d_in[6];
    const float* a_param = (const float*)d_in[7];

    float* y  = (float*)d_out;
    char*  ws = (char*)d_ws;
    f16*   wtin  = (f16*)(ws + OFF_WTIN);
    f16*   wta   = (f16*)(ws + OFF_WTA);
    float* msp2  = (float*)(ws + OFF_MSP);
    f16*   xh    = (f16*)(ws + OFF_XH);
    f16*   apfx  = (f16*)(ws + OFF_APFX);
    float* sumA  = (float*)(ws + OFF_SUMA);
    float* sumY  = (float*)(ws + OFF_SUMY);
    float* carry = (float*)(ws + OFF_CARRY);

    prep_weights<<<dim3(16, 16, 16), 256, 0, stream>>>(w_in, w_a, wtin, wta);
    prep_msp<<<dim3(D_ / 256), 256, 0, stream>>>(a_param, msp2);
    prep_xh<<<dim3(2048), 256, 0, stream>>>(x, xh);
    gemm_gates<<<dim3(M_ / BM, BW_ / BN, H_), 256, 0, stream>>>(
        xh, segpos, wtin, wta, b_in, b_a, msp2, apfx, sumA, sumY, y);
    scan_mid<<<dim3(D_ / 256, B_), 256, 0, stream>>>(sumA, sumY, carry);
    scan_apply<<<dim3(4096), 256, 0, stream>>>(carry, apfx, y);
}

// Round 4
// 277.825 us; speedup vs baseline: 1.4863x; 1.0228x over previous
//
#include <hip/hip_runtime.h>
#include <hip/hip_bf16.h>

typedef _Float16 f16;
typedef _Float16 f16x4 __attribute__((ext_vector_type(4)));
typedef _Float16 f16x8 __attribute__((ext_vector_type(8)));
typedef float f32x4 __attribute__((ext_vector_type(4)));

#define B_  4
#define L_  2048
#define D_  4096
#define H_  8
#define BW_ 512
#define M_  (B_*L_)      // 8192
#define CHUNK 128
#define NCH (L_/CHUNK)   // 16
#define LOG2E 1.4426950408889634f

// workspace layout (bytes)
static const size_t OFF_WTIN  = 0;                 // H*BW*BW fp16 = 4MB, transposed [h][n][k]
static const size_t OFF_WTA   = 4ull<<20;          // 4MB
static const size_t OFF_MSP   = 8ull<<20;          // D_ f32 (16KB)  (pre-scaled by log2e)
static const size_t OFF_XH    = 9ull<<20;          // M*D fp16 = 64MB
static const size_t OFF_APFX  = 73ull<<20;         // M*D fp16 = 64MB
static const size_t OFF_SUMA  = 137ull<<20;        // B*NCH*D f32 = 1MB
static const size_t OFF_SUMY  = 138ull<<20;
static const size_t OFF_CARRY = 139ull<<20;

__device__ __forceinline__ void gl16(const void* g, void* l) {
    __builtin_amdgcn_global_load_lds(
        (const __attribute__((address_space(1))) unsigned int*)g,
        (__attribute__((address_space(3))) unsigned int*)l, 16, 0, 0);
}

// ---------- prep: transpose+convert weights to fp16 [h][n][k] ----------
__global__ __launch_bounds__(256)
void prep_weights(const float* __restrict__ w_in, const float* __restrict__ w_a,
                  f16* __restrict__ wtin, f16* __restrict__ wta) {
    __shared__ float tile[32][33];
    int g = blockIdx.z >> 3;          // 0 = in, 1 = a
    int h = blockIdx.z & 7;
    const float* src = (g ? w_a : w_in) + (size_t)h * BW_ * BW_;
    f16* dst = (g ? wta : wtin) + (size_t)h * BW_ * BW_;
    int i0 = blockIdx.y * 32, j0 = blockIdx.x * 32;
    int tx = threadIdx.x & 31, ty = threadIdx.x >> 5;
#pragma unroll
    for (int q = 0; q < 4; ++q) {
        int i = ty + q * 8;
        tile[i][tx] = src[(size_t)(i0 + i) * BW_ + j0 + tx];
    }
    __syncthreads();
#pragma unroll
    for (int q = 0; q < 4; ++q) {
        int j = ty + q * 8;
        dst[(size_t)(j0 + j) * BW_ + i0 + tx] = (f16)tile[tx][j];
    }
}

// ---------- prep: msp2[d] = -8 * softplus(a_param[d]) * log2(e) ----------
__global__ __launch_bounds__(256)
void prep_msp(const float* __restrict__ a_param, float* __restrict__ msp2) {
    int d = blockIdx.x * 256 + threadIdx.x;
    float v = a_param[d];
    msp2[d] = -8.f * log1pf(expf(v)) * LOG2E;
}

// ---------- prep: x -> fp16 ----------
__global__ __launch_bounds__(256)
void prep_xh(const float* __restrict__ x, f16* __restrict__ xh) {
    size_t i = ((size_t)blockIdx.x * 256 + threadIdx.x) * 8;
    size_t stride = (size_t)gridDim.x * 256 * 8;
    for (; i < (size_t)M_ * D_; i += stride) {
        f32x4 v0 = *(const f32x4*)(x + i);
        f32x4 v1 = *(const f32x4*)(x + i + 4);
        f16x8 hv;
        hv[0] = (f16)v0.x; hv[1] = (f16)v0.y; hv[2] = (f16)v0.z; hv[3] = (f16)v0.w;
        hv[4] = (f16)v1.x; hv[5] = (f16)v1.y; hv[6] = (f16)v1.z; hv[7] = (f16)v1.w;
        *(f16x8*)(xh + i) = hv;
    }
}

// ---------- fused gate GEMM + epilogue + chunk-local scan ----------
// BM=128 (= one scan chunk), BN=64, BK=64, 4 waves (2x2), mfma 16x16x32 f16
// 2-phase double-buffered global_load_lds pipeline (T3-min), one barrier/K-step
#define BM 128
#define BN 64
#define BKK 64
#define BUFB 32768   // bytes per staging buffer: As 16K | Bsx 8K | Bsa 8K

// LDS: staging dbuf 2*32768 = 65536.  Scan overlay reuses it after the K-loop:
//  a_s[128][65]f32 @0 (33280) | xn_s[128][66]f16 @33280 (16896) |
//  segA[4][72]f32 @50176 | segY[4][72]f32 @51328  -> 52480 total
#define SMEM_BYTES 65536

__global__ __launch_bounds__(256)
void gemm_gates(const f16*   __restrict__ xh,
                const int*   __restrict__ segpos,
                const f16*   __restrict__ wtin,
                const f16*   __restrict__ wta,
                const float* __restrict__ b_in,
                const float* __restrict__ b_a,
                const float* __restrict__ msp2,
                f16*   __restrict__ apfx,
                float* __restrict__ sumA,
                float* __restrict__ sumY,
                float* __restrict__ yloc /* = d_out */) {
    __shared__ __align__(16) char smem[SMEM_BYTES];
    float* a_s  = (float*)smem;               // [128][65]
    f16*   xn_s = (f16*)(smem + 33280);       // [128][66]
    float* segA = (float*)(smem + 50176);     // [4][72]
    float* segY = (float*)(smem + 51328);     // [4][72]

    const int tid  = threadIdx.x;
    const int m0   = blockIdx.x * BM;
    const int n0   = blockIdx.y * BN;
    const int h    = blockIdx.z;
    const int lane = tid & 63;
    const int wid  = tid >> 6;
    const int wr   = wid >> 1;
    const int wc   = wid & 1;

    f32x4 accX[4][2] = {};
    f32x4 accA[4][2] = {};

    // staging maps: physical col pc holds logical col pc ^ ((row&7)<<3);
    // source column pre-swizzled (m173/m201 pattern)
    const int grow  = lane >> 3;
    const int gcolS = (((lane & 7) ^ grow) << 3);
    const f16* aSrc  = xh   + (size_t)(m0 + wid * 32 + grow) * D_ + h * BW_ + gcolS;
    const f16* bxSrc = wtin + ((size_t)h * BW_ + n0 + wid * 16 + grow) * BW_ + gcolS;
    const f16* baSrc = wta  + ((size_t)h * BW_ + n0 + wid * 16 + grow) * BW_ + gcolS;

    const int swz  = (lane & 7) << 3;        // read-side XOR (involution)
    const int kx   = (lane >> 4) << 3;       // 0,8,16,24
    const int arow = wr * 64 + (lane & 15);
    const int brow = wc * 32 + (lane & 15);

    // reset-flag bitmask for this thread's 16 epilogue rows (replaces LDS rst_s)
    const int rowb = wr * 64 + ((lane >> 4) << 2);
    int rmask = 0;
#pragma unroll
    for (int fm = 0; fm < 4; ++fm)
#pragma unroll
        for (int reg = 0; reg < 4; ++reg)
            if (segpos[m0 + rowb + fm * 16 + reg] == 0) rmask |= 1 << (fm * 4 + reg);

    // ---- 2-phase pipelined K-loop ----
    {
        // prologue: stage tile 0 into buf0
        {
            char* base = smem;
            f16* Asb = (f16*)base;
            f16* Bxb = (f16*)(base + 16384);
            f16* Bab = (f16*)(base + 24576);
#pragma unroll
            for (int q = 0; q < 4; ++q)
                gl16(aSrc + (size_t)q * 8 * D_, &Asb[(wid * 32 + q * 8) * 64]);
#pragma unroll
            for (int q = 0; q < 2; ++q) {
                gl16(bxSrc + (size_t)q * 8 * BW_, &Bxb[(wid * 16 + q * 8) * 64]);
                gl16(baSrc + (size_t)q * 8 * BW_, &Bab[(wid * 16 + q * 8) * 64]);
            }
        }
        asm volatile("s_waitcnt vmcnt(0)" ::: "memory");
        __builtin_amdgcn_s_barrier();

#pragma unroll
        for (int t = 0; t < BW_ / BKK; ++t) {
            const int cur = t & 1;
            // issue next-tile loads into the other buffer (stay in flight
            // across the whole compute phase)
            if (t + 1 < BW_ / BKK) {
                const int k1 = (t + 1) * BKK;
                char* base = smem + (cur ^ 1) * BUFB;
                f16* Asb = (f16*)base;
                f16* Bxb = (f16*)(base + 16384);
                f16* Bab = (f16*)(base + 24576);
#pragma unroll
                for (int q = 0; q < 4; ++q)
                    gl16(aSrc + k1 + (size_t)q * 8 * D_, &Asb[(wid * 32 + q * 8) * 64]);
#pragma unroll
                for (int q = 0; q < 2; ++q) {
                    gl16(bxSrc + k1 + (size_t)q * 8 * BW_, &Bxb[(wid * 16 + q * 8) * 64]);
                    gl16(baSrc + k1 + (size_t)q * 8 * BW_, &Bab[(wid * 16 + q * 8) * 64]);
                }
            }
            // compute current buffer
            const f16* Asb = (const f16*)(smem + cur * BUFB);
            const f16* Bxb = (const f16*)(smem + cur * BUFB + 16384);
            const f16* Bab = (const f16*)(smem + cur * BUFB + 24576);
#pragma unroll
            for (int kk = 0; kk < BKK; kk += 32) {
                const int kcolS = (kk + kx) ^ swz;
                f16x8 af[4];
#pragma unroll
                for (int fm = 0; fm < 4; ++fm)
                    af[fm] = *(const f16x8*)&Asb[(arow + fm * 16) * 64 + kcolS];
#pragma unroll
                for (int fn = 0; fn < 2; ++fn) {
                    f16x8 bx = *(const f16x8*)&Bxb[(brow + fn * 16) * 64 + kcolS];
                    f16x8 ba = *(const f16x8*)&Bab[(brow + fn * 16) * 64 + kcolS];
#pragma unroll
                    for (int fm = 0; fm < 4; ++fm) {
                        accX[fm][fn] = __builtin_amdgcn_mfma_f32_16x16x32_f16(af[fm], bx, accX[fm][fn], 0, 0, 0);
                        accA[fm][fn] = __builtin_amdgcn_mfma_f32_16x16x32_f16(af[fm], ba, accA[fm][fn], 0, 0, 0);
                    }
                }
            }
            // single drain+barrier per K-step, after compute: prefetch loads
            // overlapped with the MFMA phase above
            asm volatile("s_waitcnt vmcnt(0)" ::: "memory");
            __builtin_amdgcn_s_barrier();
        }
    }

    // ---- pass A: epilogue math, deposit a (f32) + xn (f16) into LDS ----
    // C/D layout: col = lane&15, row = (lane>>4)*4 + reg  [m89-verified]
    {
#pragma unroll
        for (int fn = 0; fn < 2; ++fn) {
            const int ctile = wc * 32 + fn * 16 + (lane & 15);
            const int j = n0 + ctile;
            const int d = h * BW_ + j;
            const float bx = b_in[d];
            const float ba = b_a[d];
            const float mspd = msp2[d];
#pragma unroll
            for (int fm = 0; fm < 4; ++fm) {
#pragma unroll
                for (int reg = 0; reg < 4; ++reg) {
                    const int rowt = rowb + fm * 16 + reg;       // 0..127
                    const int r = m0 + rowt;
                    float gxl = accX[fm][fn][reg] + bx;
                    float gal = accA[fm][fn][reg] + ba;
                    float gx = __builtin_amdgcn_rcpf(1.f + __builtin_amdgcn_exp2f(-gxl * LOG2E));
                    float ga = __builtin_amdgcn_rcpf(1.f + __builtin_amdgcn_exp2f(-gal * LOG2E));
                    float a  = __builtin_amdgcn_exp2f(mspd * ga);
                    float a2 = a * a;                            // = exp(2*log_a)
                    float mult = __builtin_amdgcn_sqrtf(1.f + 1e-6f - a2);
                    float rv = ((rmask >> (fm * 4 + reg)) & 1) ? 1.f : 0.f;
                    a *= (1.f - rv);
                    mult = rv + (1.f - rv) * mult;
                    float xv = (float)xh[(size_t)r * D_ + d];
                    a_s[rowt * 65 + ctile] = a;
                    xn_s[rowt * 66 + ctile] = (f16)(xv * gx * mult);
                }
            }
        }
    }
    __syncthreads();

    // ---- pass B: per-segment (32-step) summaries ----
    const int scol = tid & 63;
    const int sseg = tid >> 6;
    {
        float A = 1.f, yv = 0.f;
#pragma unroll 4
        for (int t = sseg * 32; t < sseg * 32 + 32; ++t) {
            float a  = a_s[t * 65 + scol];
            float xn = (float)xn_s[t * 66 + scol];
            yv = fmaf(a, yv, xn);
            A *= a;
        }
        segA[sseg * 72 + scol] = A;
        segY[sseg * 72 + scol] = yv;
    }
    __syncthreads();

    // ---- pass C: carry-in per segment, rewalk, write ylocal + Apfx ----
    {
        float cy = 0.f, pA = 1.f;
        for (int s = 0; s < sseg; ++s) {
            float As_ = segA[s * 72 + scol];
            float Ys_ = segY[s * 72 + scol];
            cy = fmaf(As_, cy, Ys_);
            pA *= As_;
        }
        float Arun = 1.f, yv = cy;
        const size_t obase = (size_t)(m0 + sseg * 32) * D_ + h * BW_ + n0 + scol;
#pragma unroll 4
        for (int i = 0; i < 32; ++i) {
            const int t = sseg * 32 + i;
            float a  = a_s[t * 65 + scol];
            float xn = (float)xn_s[t * 66 + scol];
            yv = fmaf(a, yv, xn);
            Arun *= a;
            size_t o = obase + (size_t)i * D_;
            yloc[o] = yv;
            apfx[o] = (f16)(pA * Arun);
        }
        if (sseg == 3) {
            const int bb = m0 >> 11;             // batch
            const int cc = (m0 & 2047) >> 7;     // chunk in batch
            size_t si = ((size_t)bb * NCH + cc) * D_ + h * BW_ + n0 + scol;
            sumA[si] = pA * Arun;
            sumY[si] = yv;
        }
    }
}

// ---------- scan phase 2: scan over chunk summaries -> carry-in per chunk ----------
__global__ __launch_bounds__(256)
void scan_mid(const float* __restrict__ sumA, const float* __restrict__ sumY,
              float* __restrict__ carry) {
    int d = blockIdx.x * 256 + threadIdx.x;
    int b = blockIdx.y;
    float hcur = 0.f;
#pragma unroll
    for (int c = 0; c < NCH; ++c) {
        size_t si = ((size_t)b * NCH + c) * D_ + d;
        carry[si] = hcur;
        hcur = fmaf(sumA[si], hcur, sumY[si]);
    }
}

// ---------- scan phase 3: elementwise apply y = ylocal + carry * Apfx ----------
__global__ __launch_bounds__(256)
void scan_apply(const float* __restrict__ carry, const f16* __restrict__ apfx,
                float* __restrict__ y) {
    size_t i4 = (size_t)blockIdx.x * 256 + threadIdx.x;
    const size_t stride = (size_t)gridDim.x * 256;
    const size_t n4 = (size_t)M_ * D_ / 4;
    for (; i4 < n4; i4 += stride) {
        size_t i = i4 * 4;
        size_t row = i >> 12;
        int d = (int)(i & 4095);
        int b = (int)(row >> 11);
        int c = ((int)row & 2047) >> 7;
        const float* cp = carry + (((size_t)(b * NCH + c)) << 12) + d;
        f32x4 yv = *(const f32x4*)(y + i);
        f16x4 ap = *(const f16x4*)(apfx + i);
        f32x4 cv = *(const f32x4*)cp;
        yv.x = fmaf(cv.x, (float)ap[0], yv.x);
        yv.y = fmaf(cv.y, (float)ap[1], yv.y);
        yv.z = fmaf(cv.z, (float)ap[2], yv.z);
        yv.w = fmaf(cv.w, (float)ap[3], yv.w);
        *(f32x4*)(y + i) = yv;
    }
}

extern "C" void kernel_launch(void* const* d_in, const int* in_sizes, int n_in,
                              void* d_out, int out_size, void* d_ws, size_t ws_size,
                              hipStream_t stream) {
    const float* x       = (const float*)d_in[0];
    const int*   segpos  = (const int*)d_in[1];
    // d_in[2] = prev_h (unused by reference for L>1 path)
    const float* w_in    = (const float*)d_in[3];
    const float* b_in    = (const float*)d_in[4];
    const float* w_a     = (const float*)d_in[5];
    const float* b_a     = (const float*)d_in[6];
    const float* a_param = (const float*)d_in[7];

    float* y  = (float*)d_out;
    char*  ws = (char*)d_ws;
    f16*   wtin  = (f16*)(ws + OFF_WTIN);
    f16*   wta   = (f16*)(ws + OFF_WTA);
    float* msp2  = (float*)(ws + OFF_MSP);
    f16*   xh    = (f16*)(ws + OFF_XH);
    f16*   apfx  = (f16*)(ws + OFF_APFX);
    float* sumA  = (float*)(ws + OFF_SUMA);
    float* sumY  = (float*)(ws + OFF_SUMY);
    float* carry = (float*)(ws + OFF_CARRY);

    prep_weights<<<dim3(16, 16, 16), 256, 0, stream>>>(w_in, w_a, wtin, wta);
    prep_msp<<<dim3(D_ / 256), 256, 0, stream>>>(a_param, msp2);
    prep_xh<<<dim3(2048), 256, 0, stream>>>(x, xh);
    gemm_gates<<<dim3(M_ / BM, BW_ / BN, H_), 256, 0, stream>>>(
        xh, segpos, wtin, wta, b_in, b_a, msp2, apfx, sumA, sumY, y);
    scan_mid<<<dim3(D_ / 256, B_), 256, 0, stream>>>(sumA, sumY, carry);
    scan_apply<<<dim3(4096), 256, 0, stream>>>(carry, apfx, y);
}

// Round 5
// 238.970 us; speedup vs baseline: 1.7279x; 1.1626x over previous
//
#include <hip/hip_runtime.h>
#include <hip/hip_bf16.h>

typedef _Float16 f16;
typedef _Float16 f16x2 __attribute__((ext_vector_type(2)));
typedef _Float16 f16x4 __attribute__((ext_vector_type(4)));
typedef _Float16 f16x8 __attribute__((ext_vector_type(8)));
typedef float f32x4 __attribute__((ext_vector_type(4)));

#define B_  4
#define L_  2048
#define D_  4096
#define H_  8
#define BW_ 512
#define M_  (B_*L_)      // 8192
#define CHUNK 128
#define NCH (L_/CHUNK)   // 16
#define LOG2E 1.4426950408889634f

// workspace layout (bytes)
static const size_t OFF_WTIN  = 0;                 // H*BW*BW fp16 = 4MB, transposed [h][n][k]
static const size_t OFF_WTA   = 4ull<<20;          // 4MB
static const size_t OFF_MSP   = 8ull<<20;          // D_ f32 (16KB)  (pre-scaled by log2e)
static const size_t OFF_XH    = 9ull<<20;          // M*D fp16 = 64MB
static const size_t OFF_YLAP  = 73ull<<20;         // M*D f16x2 (yloc,apfx) = 134MB
static const size_t OFF_SUMA  = 208ull<<20;        // B*NCH*D f32 = 1MB
static const size_t OFF_SUMY  = 209ull<<20;
static const size_t OFF_CARRY = 210ull<<20;

__device__ __forceinline__ void gl16(const void* g, void* l) {
    __builtin_amdgcn_global_load_lds(
        (const __attribute__((address_space(1))) unsigned int*)g,
        (__attribute__((address_space(3))) unsigned int*)l, 16, 0, 0);
}

// ---------- prep: transpose+convert weights to fp16 [h][n][k] ----------
__global__ __launch_bounds__(256)
void prep_weights(const float* __restrict__ w_in, const float* __restrict__ w_a,
                  f16* __restrict__ wtin, f16* __restrict__ wta) {
    __shared__ float tile[32][33];
    int g = blockIdx.z >> 3;          // 0 = in, 1 = a
    int h = blockIdx.z & 7;
    const float* src = (g ? w_a : w_in) + (size_t)h * BW_ * BW_;
    f16* dst = (g ? wta : wtin) + (size_t)h * BW_ * BW_;
    int i0 = blockIdx.y * 32, j0 = blockIdx.x * 32;
    int tx = threadIdx.x & 31, ty = threadIdx.x >> 5;
#pragma unroll
    for (int q = 0; q < 4; ++q) {
        int i = ty + q * 8;
        tile[i][tx] = src[(size_t)(i0 + i) * BW_ + j0 + tx];
    }
    __syncthreads();
#pragma unroll
    for (int q = 0; q < 4; ++q) {
        int j = ty + q * 8;
        dst[(size_t)(j0 + j) * BW_ + i0 + tx] = (f16)tile[tx][j];
    }
}

// ---------- prep: msp2[d] = -8 * softplus(a_param[d]) * log2(e) ----------
__global__ __launch_bounds__(256)
void prep_msp(const float* __restrict__ a_param, float* __restrict__ msp2) {
    int d = blockIdx.x * 256 + threadIdx.x;
    float v = a_param[d];
    msp2[d] = -8.f * log1pf(expf(v)) * LOG2E;
}

// ---------- prep: x -> fp16 ----------
__global__ __launch_bounds__(256)
void prep_xh(const float* __restrict__ x, f16* __restrict__ xh) {
    size_t i = ((size_t)blockIdx.x * 256 + threadIdx.x) * 8;
    size_t stride = (size_t)gridDim.x * 256 * 8;
    for (; i < (size_t)M_ * D_; i += stride) {
        f32x4 v0 = *(const f32x4*)(x + i);
        f32x4 v1 = *(const f32x4*)(x + i + 4);
        f16x8 hv;
        hv[0] = (f16)v0.x; hv[1] = (f16)v0.y; hv[2] = (f16)v0.z; hv[3] = (f16)v0.w;
        hv[4] = (f16)v1.x; hv[5] = (f16)v1.y; hv[6] = (f16)v1.z; hv[7] = (f16)v1.w;
        *(f16x8*)(xh + i) = hv;
    }
}

// ---------- fused gate GEMM + epilogue + chunk-local scan ----------
// BM=128 (= one scan chunk), BN=64, BK=64, 4 waves (2x2), mfma 16x16x32 f16
// counted-vmcnt double-buffered pipeline; K-tile order permuted so the tile
// covering cols [n0,n0+64) is computed LAST -> its LDS A-tile = epilogue xv.
#define BM 128
#define BN 64
#define BKK 64
#define NT (BW_/BKK)     // 8 K-tiles
#define BUFB 32768       // bytes per staging buffer: As 16K | Bsx 8K | Bsa 8K
#define SMEM_BYTES 65536

__global__ __launch_bounds__(256)
void gemm_gates(const f16*   __restrict__ xh,
                const int*   __restrict__ segpos,
                const f16*   __restrict__ wtin,
                const f16*   __restrict__ wta,
                const float* __restrict__ b_in,
                const float* __restrict__ b_a,
                const float* __restrict__ msp2,
                f16x2* __restrict__ ylap,
                float* __restrict__ sumA,
                float* __restrict__ sumY) {
    __shared__ __align__(16) char smem[SMEM_BYTES];
    // scan overlay (after K-loop):
    float* a_s  = (float*)smem;               // [128][65]
    f16*   xn_s = (f16*)(smem + 33280);       // [128][66]
    float* segA = (float*)(smem + 50176);     // [4][72]
    float* segY = (float*)(smem + 51328);     // [4][72]

    const int tid  = threadIdx.x;
    const int m0   = blockIdx.x * BM;
    const int n0   = blockIdx.y * BN;
    const int h    = blockIdx.z;
    const int lane = tid & 63;
    const int wid  = tid >> 6;
    const int wr   = wid >> 1;
    const int wc   = wid & 1;

    f32x4 accX[4][2] = {};
    f32x4 accA[4][2] = {};

    // staging maps (source col pre-swizzled; LDS dest linear — m173/m201)
    const int grow  = lane >> 3;
    const int gcolS = (((lane & 7) ^ grow) << 3);
    const f16* aSrc  = xh   + (size_t)(m0 + wid * 32 + grow) * D_ + h * BW_ + gcolS;
    const f16* bxSrc = wtin + ((size_t)h * BW_ + n0 + wid * 16 + grow) * BW_ + gcolS;
    const f16* baSrc = wta  + ((size_t)h * BW_ + n0 + wid * 16 + grow) * BW_ + gcolS;

    const int swz  = (lane & 7) << 3;        // read-side XOR (involution)
    const int kx   = (lane >> 4) << 3;       // 0,8,16,24
    const int arow = wr * 64 + (lane & 15);
    const int brow = wc * 32 + (lane & 15);

    // reset-flag bitmask for this thread's 16 epilogue rows
    const int rowb = wr * 64 + ((lane >> 4) << 2);
    int rmask = 0;
#pragma unroll
    for (int fm = 0; fm < 4; ++fm)
#pragma unroll
        for (int reg = 0; reg < 4; ++reg)
            if (segpos[m0 + rowb + fm * 16 + reg] == 0) rmask |= 1 << (fm * 4 + reg);

    const int txo = (n0 >> 6) + 1;   // permutation offset: tile (n0>>6) goes last

    // prologue: stage permuted tile 0 into buf0
    {
        const int k0 = ((txo) & (NT - 1)) * BKK;
        char* base = smem;
        f16* Asb = (f16*)base;
        f16* Bxb = (f16*)(base + 16384);
        f16* Bab = (f16*)(base + 24576);
#pragma unroll
        for (int q = 0; q < 4; ++q)
            gl16(aSrc + k0 + (size_t)q * 8 * D_, &Asb[(wid * 32 + q * 8) * 64]);
#pragma unroll
        for (int q = 0; q < 2; ++q) {
            gl16(bxSrc + k0 + (size_t)q * 8 * BW_, &Bxb[(wid * 16 + q * 8) * 64]);
            gl16(baSrc + k0 + (size_t)q * 8 * BW_, &Bab[(wid * 16 + q * 8) * 64]);
        }
    }

#pragma unroll
    for (int t = 0; t < NT; ++t) {
        const int cur = t & 1;
        if (t + 1 < NT) {
            // issue next-tile loads (8/wave); they stay in flight through compute
            const int k1 = ((t + 1 + txo) & (NT - 1)) * BKK;
            char* base = smem + (cur ^ 1) * BUFB;
            f16* Asb = (f16*)base;
            f16* Bxb = (f16*)(base + 16384);
            f16* Bab = (f16*)(base + 24576);
#pragma unroll
            for (int q = 0; q < 4; ++q)
                gl16(aSrc + k1 + (size_t)q * 8 * D_, &Asb[(wid * 32 + q * 8) * 64]);
#pragma unroll
            for (int q = 0; q < 2; ++q) {
                gl16(bxSrc + k1 + (size_t)q * 8 * BW_, &Bxb[(wid * 16 + q * 8) * 64]);
                gl16(baSrc + k1 + (size_t)q * 8 * BW_, &Bab[(wid * 16 + q * 8) * 64]);
            }
            asm volatile("s_waitcnt vmcnt(8)" ::: "memory");  // prev tile landed
        } else {
            asm volatile("s_waitcnt vmcnt(0)" ::: "memory");  // last tile: drain
        }
        __builtin_amdgcn_s_barrier();          // all waves' current tile ready
        __builtin_amdgcn_sched_barrier(0);

        const f16* Asb = (const f16*)(smem + cur * BUFB);
        const f16* Bxb = (const f16*)(smem + cur * BUFB + 16384);
        const f16* Bab = (const f16*)(smem + cur * BUFB + 24576);
#pragma unroll
        for (int kk = 0; kk < BKK; kk += 32) {
            const int kcolS = (kk + kx) ^ swz;
            f16x8 af[4];
#pragma unroll
            for (int fm = 0; fm < 4; ++fm)
                af[fm] = *(const f16x8*)&Asb[(arow + fm * 16) * 64 + kcolS];
#pragma unroll
            for (int fn = 0; fn < 2; ++fn) {
                f16x8 bx = *(const f16x8*)&Bxb[(brow + fn * 16) * 64 + kcolS];
                f16x8 ba = *(const f16x8*)&Bab[(brow + fn * 16) * 64 + kcolS];
#pragma unroll
                for (int fm = 0; fm < 4; ++fm) {
                    accX[fm][fn] = __builtin_amdgcn_mfma_f32_16x16x32_f16(af[fm], bx, accX[fm][fn], 0, 0, 0);
                    accA[fm][fn] = __builtin_amdgcn_mfma_f32_16x16x32_f16(af[fm], ba, accA[fm][fn], 0, 0, 0);
                }
            }
        }
        __builtin_amdgcn_sched_barrier(0);
        __builtin_amdgcn_s_barrier();          // reads done before next overwrite
    }

    // ---- xv harvest: last-computed buffer (buf[(NT-1)&1]=buf1) holds A-tile
    // cols [n0,n0+64) — exactly the x values the epilogue needs.
    const f16* As1 = (const f16*)(smem + ((NT - 1) & 1) * BUFB);
    f16 xvv[2][4][4];
#pragma unroll
    for (int fn = 0; fn < 2; ++fn) {
        const int ctile = wc * 32 + fn * 16 + (lane & 15);
#pragma unroll
        for (int fm = 0; fm < 4; ++fm)
#pragma unroll
            for (int reg = 0; reg < 4; ++reg) {
                const int rowt = rowb + fm * 16 + reg;
                xvv[fn][fm][reg] = As1[rowt * 64 + (ctile ^ ((rowt & 7) << 3))];
            }
    }
    __syncthreads();   // xv in regs before overlay writes

    // ---- pass A: epilogue math, deposit a (f32) + xn (f16) into LDS ----
    // C/D layout: col = lane&15, row = (lane>>4)*4 + reg  [m89-verified]
    {
#pragma unroll
        for (int fn = 0; fn < 2; ++fn) {
            const int ctile = wc * 32 + fn * 16 + (lane & 15);
            const int d = h * BW_ + n0 + ctile;
            const float bx = b_in[d];
            const float ba = b_a[d];
            const float mspd = msp2[d];
#pragma unroll
            for (int fm = 0; fm < 4; ++fm) {
#pragma unroll
                for (int reg = 0; reg < 4; ++reg) {
                    const int rowt = rowb + fm * 16 + reg;       // 0..127
                    float gxl = accX[fm][fn][reg] + bx;
                    float gal = accA[fm][fn][reg] + ba;
                    float gx = __builtin_amdgcn_rcpf(1.f + __builtin_amdgcn_exp2f(-gxl * LOG2E));
                    float ga = __builtin_amdgcn_rcpf(1.f + __builtin_amdgcn_exp2f(-gal * LOG2E));
                    float a  = __builtin_amdgcn_exp2f(mspd * ga);
                    float a2 = a * a;                            // = exp(2*log_a)
                    float mult = __builtin_amdgcn_sqrtf(1.f + 1e-6f - a2);
                    float rv = ((rmask >> (fm * 4 + reg)) & 1) ? 1.f : 0.f;
                    a *= (1.f - rv);
                    mult = rv + (1.f - rv) * mult;
                    float xv = (float)xvv[fn][fm][reg];
                    a_s[rowt * 65 + ctile] = a;
                    xn_s[rowt * 66 + ctile] = (f16)(xv * gx * mult);
                }
            }
        }
    }
    __syncthreads();

    // ---- pass B: per-segment (32-step) summaries ----
    const int scol = tid & 63;
    const int sseg = tid >> 6;
    {
        float A = 1.f, yv = 0.f;
#pragma unroll 4
        for (int t = sseg * 32; t < sseg * 32 + 32; ++t) {
            float a  = a_s[t * 65 + scol];
            float xn = (float)xn_s[t * 66 + scol];
            yv = fmaf(a, yv, xn);
            A *= a;
        }
        segA[sseg * 72 + scol] = A;
        segY[sseg * 72 + scol] = yv;
    }
    __syncthreads();

    // ---- pass C: carry-in per segment, rewalk, write packed (yloc, apfx) ----
    {
        float cy = 0.f, pA = 1.f;
        for (int s = 0; s < sseg; ++s) {
            float As_ = segA[s * 72 + scol];
            float Ys_ = segY[s * 72 + scol];
            cy = fmaf(As_, cy, Ys_);
            pA *= As_;
        }
        float Arun = 1.f, yv = cy;
        const size_t obase = (size_t)(m0 + sseg * 32) * D_ + h * BW_ + n0 + scol;
#pragma unroll 4
        for (int i = 0; i < 32; ++i) {
            const int t = sseg * 32 + i;
            float a  = a_s[t * 65 + scol];
            float xn = (float)xn_s[t * 66 + scol];
            yv = fmaf(a, yv, xn);
            Arun *= a;
            f16x2 p;
            p[0] = (f16)yv;
            p[1] = (f16)(pA * Arun);
            ylap[obase + (size_t)i * D_] = p;
        }
        if (sseg == 3) {
            const int bb = m0 >> 11;             // batch
            const int cc = (m0 & 2047) >> 7;     // chunk in batch
            size_t si = ((size_t)bb * NCH + cc) * D_ + h * BW_ + n0 + scol;
            sumA[si] = pA * Arun;
            sumY[si] = yv;
        }
    }
}

// ---------- scan phase 2: scan over chunk summaries -> carry-in per chunk ----------
__global__ __launch_bounds__(256)
void scan_mid(const float* __restrict__ sumA, const float* __restrict__ sumY,
              float* __restrict__ carry) {
    int d = blockIdx.x * 256 + threadIdx.x;
    int b = blockIdx.y;
    float hcur = 0.f;
#pragma unroll
    for (int c = 0; c < NCH; ++c) {
        size_t si = ((size_t)b * NCH + c) * D_ + d;
        carry[si] = hcur;
        hcur = fmaf(sumA[si], hcur, sumY[si]);
    }
}

// ---------- scan phase 3: elementwise y = yloc + carry * apfx ----------
__global__ __launch_bounds__(256)
void scan_apply(const float* __restrict__ carry, const f16x2* __restrict__ ylap,
                float* __restrict__ y) {
    size_t i4 = (size_t)blockIdx.x * 256 + threadIdx.x;
    const size_t stride = (size_t)gridDim.x * 256;
    const size_t n4 = (size_t)M_ * D_ / 4;
    for (; i4 < n4; i4 += stride) {
        size_t i = i4 * 4;
        size_t row = i >> 12;
        int d = (int)(i & 4095);
        int b = (int)(row >> 11);
        int c = ((int)row & 2047) >> 7;
        const float* cp = carry + (((size_t)(b * NCH + c)) << 12) + d;
        f32x4 cv = *(const f32x4*)cp;
        f16x8 pk = *(const f16x8*)(ylap + i);   // [y0,a0,y1,a1,y2,a2,y3,a3]
        f32x4 o;
        o.x = fmaf(cv.x, (float)pk[1], (float)pk[0]);
        o.y = fmaf(cv.y, (float)pk[3], (float)pk[2]);
        o.z = fmaf(cv.z, (float)pk[5], (float)pk[4]);
        o.w = fmaf(cv.w, (float)pk[7], (float)pk[6]);
        *(f32x4*)(y + i) = o;
    }
}

extern "C" void kernel_launch(void* const* d_in, const int* in_sizes, int n_in,
                              void* d_out, int out_size, void* d_ws, size_t ws_size,
                              hipStream_t stream) {
    const float* x       = (const float*)d_in[0];
    const int*   segpos  = (const int*)d_in[1];
    // d_in[2] = prev_h (unused by reference for L>1 path)
    const float* w_in    = (const float*)d_in[3];
    const float* b_in    = (const float*)d_in[4];
    const float* w_a     = (const float*)d_in[5];
    const float* b_a     = (const float*)d_in[6];
    const float* a_param = (const float*)d_in[7];

    float* y  = (float*)d_out;
    char*  ws = (char*)d_ws;
    f16*   wtin  = (f16*)(ws + OFF_WTIN);
    f16*   wta   = (f16*)(ws + OFF_WTA);
    float* msp2  = (float*)(ws + OFF_MSP);
    f16*   xh    = (f16*)(ws + OFF_XH);
    f16x2* ylap  = (f16x2*)(ws + OFF_YLAP);
    float* sumA  = (float*)(ws + OFF_SUMA);
    float* sumY  = (float*)(ws + OFF_SUMY);
    float* carry = (float*)(ws + OFF_CARRY);

    prep_weights<<<dim3(16, 16, 16), 256, 0, stream>>>(w_in, w_a, wtin, wta);
    prep_msp<<<dim3(D_ / 256), 256, 0, stream>>>(a_param, msp2);
    prep_xh<<<dim3(2048), 256, 0, stream>>>(x, xh);
    gemm_gates<<<dim3(M_ / BM, BW_ / BN, H_), 256, 0, stream>>>(
        xh, segpos, wtin, wta, b_in, b_a, msp2, ylap, sumA, sumY);
    scan_mid<<<dim3(D_ / 256, B_), 256, 0, stream>>>(sumA, sumY, carry);
    scan_apply<<<dim3(4096), 256, 0, stream>>>(carry, ylap, y);
}

// Round 6
// 223.527 us; speedup vs baseline: 1.8473x; 1.0691x over previous
//
#include <hip/hip_runtime.h>
#include <hip/hip_bf16.h>

typedef _Float16 f16;
typedef _Float16 f16x2 __attribute__((ext_vector_type(2)));
typedef _Float16 f16x4 __attribute__((ext_vector_type(4)));
typedef _Float16 f16x8 __attribute__((ext_vector_type(8)));
typedef float f32x4 __attribute__((ext_vector_type(4)));

#define B_  4
#define L_  2048
#define D_  4096
#define H_  8
#define BW_ 512
#define M_  (B_*L_)      // 8192
#define CHUNK 128
#define NCH (L_/CHUNK)   // 16
#define LOG2E 1.4426950408889634f

// workspace layout (bytes)
static const size_t OFF_WPK   = 0;                 // packed B frags: 8MB (both gates)
static const size_t OFF_MSP   = 8ull<<20;          // D_ f32 (16KB)  (pre-scaled by log2e)
static const size_t OFF_XH    = 9ull<<20;          // M*D fp16 = 64MB
static const size_t OFF_YLAP  = 73ull<<20;         // M*D f16x2 (yloc,apfx) = 134MB
static const size_t OFF_SUMA  = 208ull<<20;        // B*NCH*D f32 = 1MB
static const size_t OFF_SUMY  = 209ull<<20;
static const size_t OFF_CARRY = 210ull<<20;

__device__ __forceinline__ void gl16(const void* g, void* l) {
    __builtin_amdgcn_global_load_lds(
        (const __attribute__((address_space(1))) unsigned int*)g,
        (__attribute__((address_space(3))) unsigned int*)l, 16, 0, 0);
}

// ---------- prep: pack W^T into MFMA B-fragment order, f32 -> f16 ----------
// layout: wpk[((h*16 + n32)*8 + kt)*8 + fidx][lane] : f16x8
//   fidx = g*4 + fn*2 + kk2 ; fragment element e:
//   B[n = n32*32 + fn*16 + (lane&15)][k = kt*64 + kk2*32 + (lane>>4)*8 + e]
//   where B[n][k] = w[h][k][n]
__global__ __launch_bounds__(256)
void prep_wpack(const float* __restrict__ w_in, const float* __restrict__ w_a,
                f16* __restrict__ wpk) {
    const int kt  = blockIdx.x & 7;
    const int n32 = (blockIdx.x >> 3) & 15;
    const int h   = blockIdx.x >> 7;
    const int tid = threadIdx.x;
#pragma unroll
    for (int q = 0; q < 2; ++q) {
        int slot = q * 256 + tid;          // 0..511
        int lane = slot & 63;
        int fidx = slot >> 6;              // g*4 + fn*2 + kk2
        int g    = fidx >> 2;
        int fn   = (fidx >> 1) & 1;
        int kk2  = fidx & 1;
        int row = n32 * 32 + fn * 16 + (lane & 15);
        int col = kt * 64 + kk2 * 32 + ((lane >> 4) << 3);
        const float* src = (g ? w_a : w_in) + (size_t)h * BW_ * BW_;
        f16x8 v;
#pragma unroll
        for (int e = 0; e < 8; ++e)
            v[e] = (f16)src[(size_t)(col + e) * BW_ + row];
        size_t o = ((((size_t)(h * 16 + n32) * 8 + kt) * 8) + fidx) * 64 + lane;
        *(f16x8*)(wpk + o * 8) = v;
    }
}

// ---------- prep: msp2[d] = -8 * softplus(a_param[d]) * log2(e) ----------
__global__ __launch_bounds__(256)
void prep_msp(const float* __restrict__ a_param, float* __restrict__ msp2) {
    int d = blockIdx.x * 256 + threadIdx.x;
    float v = a_param[d];
    msp2[d] = -8.f * log1pf(expf(v)) * LOG2E;
}

// ---------- prep: x -> fp16 ----------
__global__ __launch_bounds__(256)
void prep_xh(const float* __restrict__ x, f16* __restrict__ xh) {
    size_t i = ((size_t)blockIdx.x * 256 + threadIdx.x) * 8;
    size_t stride = (size_t)gridDim.x * 256 * 8;
    for (; i < (size_t)M_ * D_; i += stride) {
        f32x4 v0 = *(const f32x4*)(x + i);
        f32x4 v1 = *(const f32x4*)(x + i + 4);
        f16x8 hv;
        hv[0] = (f16)v0.x; hv[1] = (f16)v0.y; hv[2] = (f16)v0.z; hv[3] = (f16)v0.w;
        hv[4] = (f16)v1.x; hv[5] = (f16)v1.y; hv[6] = (f16)v1.z; hv[7] = (f16)v1.w;
        *(f16x8*)(xh + i) = hv;
    }
}

// ---------- fused gate GEMM + epilogue + chunk-local scan ----------
// BM=128 (= one scan chunk), BN=64, BK=64, 4 waves (2x2), mfma 16x16x32 f16
// A via global_load_lds dbuf (16KB x2); B via pre-packed register fragments
// (L2-resident, coalesced). Counted vmcnt(12). K-tiles permuted so the tile
// covering cols [n0,n0+64) is LAST -> its LDS A-tile = epilogue xv.
#define BM 128
#define BN 64
#define BKK 64
#define NT (BW_/BKK)     // 8 K-tiles
#define BUFB 16384       // bytes per A staging buffer

// LDS map: staging buf0 @0, buf1 @16384 (32K total).  Post-K-loop overlay:
//  a_s[128][65]f32 @0 (33280) | xn_s[128][66]f16 @33280 (16896)
//  segA[4][72] @50176 | segY[4][72] @51328 | rst_s[128] @52480 -> 52992
#define SMEM_BYTES 52992

__global__ __launch_bounds__(256, 3)
void gemm_gates(const f16*   __restrict__ xh,
                const int*   __restrict__ segpos,
                const f16*   __restrict__ wpk,
                const float* __restrict__ b_in,
                const float* __restrict__ b_a,
                const float* __restrict__ msp2,
                f16x2* __restrict__ ylap,
                float* __restrict__ sumA,
                float* __restrict__ sumY) {
    __shared__ __align__(16) char smem[SMEM_BYTES];
    float* a_s  = (float*)smem;               // [128][65]
    f16*   xn_s = (f16*)(smem + 33280);       // [128][66]
    float* segA = (float*)(smem + 50176);     // [4][72]
    float* segY = (float*)(smem + 51328);     // [4][72]
    float* rst_s= (float*)(smem + 52480);     // [128]

    const int tid  = threadIdx.x;
    const int m0   = blockIdx.x * BM;
    const int n0   = blockIdx.y * BN;
    const int h    = blockIdx.z;
    const int lane = tid & 63;
    const int wid  = tid >> 6;
    const int wr   = wid >> 1;
    const int wc   = wid & 1;

    f32x4 accX[4][2] = {};
    f32x4 accA[4][2] = {};

    // reset flags -> LDS (region untouched by staging)
    if (tid < BM) rst_s[tid] = (segpos[m0 + tid] == 0) ? 1.f : 0.f;

    // A staging map (source col pre-swizzled; LDS dest linear — m173/m201)
    const int grow  = lane >> 3;
    const int gcolS = (((lane & 7) ^ grow) << 3);
    const f16* aSrc = xh + (size_t)(m0 + wid * 32 + grow) * D_ + h * BW_ + gcolS;

    // B packed fragment base for this wave: (h, n32 = n0/32 + wc)
    const f16* wbase = wpk + ((size_t)(h * 16) + (n0 >> 5) + wc) * 32768;

    const int swz  = (lane & 7) << 3;        // read-side XOR (involution)
    const int kx   = (lane >> 4) << 3;       // 0,8,16,24
    const int arow = wr * 64 + (lane & 15);

    const int rowb = wr * 64 + ((lane >> 4) << 2);
    const int txo = (n0 >> 6) + 1;   // permutation: tile (n0>>6) goes last

    f16x8 bfr[2][8];

    // prologue: stage permuted tile 0 (A -> buf0, B -> bfr[0])
    {
        const int k0 = (txo & (NT - 1)) * BKK;
        f16* Asb = (f16*)smem;
#pragma unroll
        for (int q = 0; q < 4; ++q)
            gl16(aSrc + k0 + (size_t)q * 8 * D_, &Asb[(wid * 32 + q * 8) * 64]);
        const f16* tp = wbase + (size_t)(txo & (NT - 1)) * 4096;
#pragma unroll
        for (int j = 0; j < 8; ++j)
            bfr[0][j] = *(const f16x8*)(tp + j * 512 + lane * 8);
    }

#pragma unroll
    for (int t = 0; t < NT; ++t) {
        const int cur = t & 1;
        if (t + 1 < NT) {
            const int kt1 = (t + 1 + txo) & (NT - 1);
            f16* Asb = (f16*)(smem + (cur ^ 1) * BUFB);
#pragma unroll
            for (int q = 0; q < 4; ++q)
                gl16(aSrc + kt1 * BKK + (size_t)q * 8 * D_, &Asb[(wid * 32 + q * 8) * 64]);
            const f16* tp = wbase + (size_t)kt1 * 4096;
#pragma unroll
            for (int j = 0; j < 8; ++j)
                bfr[cur ^ 1][j] = *(const f16x8*)(tp + j * 512 + lane * 8);
            asm volatile("s_waitcnt vmcnt(12)" ::: "memory");  // tile t landed
        } else {
            asm volatile("s_waitcnt vmcnt(0)" ::: "memory");
        }
        __builtin_amdgcn_s_barrier();          // all waves' A(t) visible
        __builtin_amdgcn_sched_barrier(0);

        const f16* Asb = (const f16*)(smem + cur * BUFB);
#pragma unroll
        for (int kk2 = 0; kk2 < 2; ++kk2) {
            const int kcolS = (kk2 * 32 + kx) ^ swz;
            f16x8 af[4];
#pragma unroll
            for (int fm = 0; fm < 4; ++fm)
                af[fm] = *(const f16x8*)&Asb[(arow + fm * 16) * 64 + kcolS];
#pragma unroll
            for (int fn = 0; fn < 2; ++fn) {
                f16x8 bx = bfr[cur][fn * 2 + kk2];
                f16x8 ba = bfr[cur][4 + fn * 2 + kk2];
#pragma unroll
                for (int fm = 0; fm < 4; ++fm) {
                    accX[fm][fn] = __builtin_amdgcn_mfma_f32_16x16x32_f16(af[fm], bx, accX[fm][fn], 0, 0, 0);
                    accA[fm][fn] = __builtin_amdgcn_mfma_f32_16x16x32_f16(af[fm], ba, accA[fm][fn], 0, 0, 0);
                }
            }
        }
        __builtin_amdgcn_sched_barrier(0);
        __builtin_amdgcn_s_barrier();          // reads done before overwrite
    }

    // ---- xv harvest: last tile (buf1) holds A cols [n0,n0+64) ----
    const f16* As1 = (const f16*)(smem + BUFB);
    f16 xvv[2][4][4];
#pragma unroll
    for (int fn = 0; fn < 2; ++fn) {
        const int ctile = wc * 32 + fn * 16 + (lane & 15);
#pragma unroll
        for (int fm = 0; fm < 4; ++fm)
#pragma unroll
            for (int reg = 0; reg < 4; ++reg) {
                const int rowt = rowb + fm * 16 + reg;
                xvv[fn][fm][reg] = As1[rowt * 64 + (ctile ^ ((rowt & 7) << 3))];
            }
    }
    __syncthreads();   // xv in regs before overlay writes

    // ---- pass A: epilogue math, deposit a (f32) + xn (f16) into LDS ----
    // C/D layout: col = lane&15, row = (lane>>4)*4 + reg  [m89-verified]
    {
#pragma unroll
        for (int fn = 0; fn < 2; ++fn) {
            const int ctile = wc * 32 + fn * 16 + (lane & 15);
            const int d = h * BW_ + n0 + ctile;
            const float bx = b_in[d];
            const float ba = b_a[d];
            const float mspd = msp2[d];
#pragma unroll
            for (int fm = 0; fm < 4; ++fm) {
#pragma unroll
                for (int reg = 0; reg < 4; ++reg) {
                    const int rowt = rowb + fm * 16 + reg;       // 0..127
                    float gxl = accX[fm][fn][reg] + bx;
                    float gal = accA[fm][fn][reg] + ba;
                    float gx = __builtin_amdgcn_rcpf(1.f + __builtin_amdgcn_exp2f(-gxl * LOG2E));
                    float ga = __builtin_amdgcn_rcpf(1.f + __builtin_amdgcn_exp2f(-gal * LOG2E));
                    float a  = __builtin_amdgcn_exp2f(mspd * ga);
                    float a2 = a * a;                            // = exp(2*log_a)
                    float mult = __builtin_amdgcn_sqrtf(1.f + 1e-6f - a2);
                    float rv = rst_s[rowt];
                    a *= (1.f - rv);
                    mult = rv + (1.f - rv) * mult;
                    float xv = (float)xvv[fn][fm][reg];
                    a_s[rowt * 65 + ctile] = a;
                    xn_s[rowt * 66 + ctile] = (f16)(xv * gx * mult);
                }
            }
        }
    }
    __syncthreads();

    // ---- pass B: per-segment (32-step) summaries ----
    const int scol = tid & 63;
    const int sseg = tid >> 6;
    {
        float A = 1.f, yv = 0.f;
#pragma unroll 4
        for (int t = sseg * 32; t < sseg * 32 + 32; ++t) {
            float a  = a_s[t * 65 + scol];
            float xn = (float)xn_s[t * 66 + scol];
            yv = fmaf(a, yv, xn);
            A *= a;
        }
        segA[sseg * 72 + scol] = A;
        segY[sseg * 72 + scol] = yv;
    }
    __syncthreads();

    // ---- pass C: carry-in per segment, rewalk, write packed (yloc, apfx) ----
    {
        float cy = 0.f, pA = 1.f;
        for (int s = 0; s < sseg; ++s) {
            float As_ = segA[s * 72 + scol];
            float Ys_ = segY[s * 72 + scol];
            cy = fmaf(As_, cy, Ys_);
            pA *= As_;
        }
        float Arun = 1.f, yv = cy;
        const size_t obase = (size_t)(m0 + sseg * 32) * D_ + h * BW_ + n0 + scol;
#pragma unroll 4
        for (int i = 0; i < 32; ++i) {
            const int t = sseg * 32 + i;
            float a  = a_s[t * 65 + scol];
            float xn = (float)xn_s[t * 66 + scol];
            yv = fmaf(a, yv, xn);
            Arun *= a;
            f16x2 p;
            p[0] = (f16)yv;
            p[1] = (f16)(pA * Arun);
            ylap[obase + (size_t)i * D_] = p;
        }
        if (sseg == 3) {
            const int bb = m0 >> 11;             // batch
            const int cc = (m0 & 2047) >> 7;     // chunk in batch
            size_t si = ((size_t)bb * NCH + cc) * D_ + h * BW_ + n0 + scol;
            sumA[si] = pA * Arun;
            sumY[si] = yv;
        }
    }
}

// ---------- scan phase 2: scan over chunk summaries -> carry-in per chunk ----------
__global__ __launch_bounds__(256)
void scan_mid(const float* __restrict__ sumA, const float* __restrict__ sumY,
              float* __restrict__ carry) {
    int d = blockIdx.x * 256 + threadIdx.x;
    int b = blockIdx.y;
    float hcur = 0.f;
#pragma unroll
    for (int c = 0; c < NCH; ++c) {
        size_t si = ((size_t)b * NCH + c) * D_ + d;
        carry[si] = hcur;
        hcur = fmaf(sumA[si], hcur, sumY[si]);
    }
}

// ---------- scan phase 3: elementwise y = yloc + carry * apfx ----------
__global__ __launch_bounds__(256)
void scan_apply(const float* __restrict__ carry, const f16x2* __restrict__ ylap,
                float* __restrict__ y) {
    size_t i4 = (size_t)blockIdx.x * 256 + threadIdx.x;
    const size_t stride = (size_t)gridDim.x * 256;
    const size_t n4 = (size_t)M_ * D_ / 4;
    for (; i4 < n4; i4 += stride) {
        size_t i = i4 * 4;
        size_t row = i >> 12;
        int d = (int)(i & 4095);
        int b = (int)(row >> 11);
        int c = ((int)row & 2047) >> 7;
        const float* cp = carry + (((size_t)(b * NCH + c)) << 12) + d;
        f32x4 cv = *(const f32x4*)cp;
        f16x8 pk = *(const f16x8*)(ylap + i);   // [y0,a0,y1,a1,y2,a2,y3,a3]
        f32x4 o;
        o.x = fmaf(cv.x, (float)pk[1], (float)pk[0]);
        o.y = fmaf(cv.y, (float)pk[3], (float)pk[2]);
        o.z = fmaf(cv.z, (float)pk[5], (float)pk[4]);
        o.w = fmaf(cv.w, (float)pk[7], (float)pk[6]);
        *(f32x4*)(y + i) = o;
    }
}

extern "C" void kernel_launch(void* const* d_in, const int* in_sizes, int n_in,
                              void* d_out, int out_size, void* d_ws, size_t ws_size,
                              hipStream_t stream) {
    const float* x       = (const float*)d_in[0];
    const int*   segpos  = (const int*)d_in[1];
    // d_in[2] = prev_h (unused by reference for L>1 path)
    const float* w_in    = (const float*)d_in[3];
    const float* b_in    = (const float*)d_in[4];
    const float* w_a     = (const float*)d_in[5];
    const float* b_a     = (const float*)d_in[6];
    const float* a_param = (const float*)d_in[7];

    float* y  = (float*)d_out;
    char*  ws = (char*)d_ws;
    f16*   wpk   = (f16*)(ws + OFF_WPK);
    float* msp2  = (float*)(ws + OFF_MSP);
    f16*   xh    = (f16*)(ws + OFF_XH);
    f16x2* ylap  = (f16x2*)(ws + OFF_YLAP);
    float* sumA  = (float*)(ws + OFF_SUMA);
    float* sumY  = (float*)(ws + OFF_SUMY);
    float* carry = (float*)(ws + OFF_CARRY);

    prep_wpack<<<dim3(1024), 256, 0, stream>>>(w_in, w_a, wpk);
    prep_msp<<<dim3(D_ / 256), 256, 0, stream>>>(a_param, msp2);
    prep_xh<<<dim3(2048), 256, 0, stream>>>(x, xh);
    gemm_gates<<<dim3(M_ / BM, BW_ / BN, H_), 256, 0, stream>>>(
        xh, segpos, wpk, b_in, b_a, msp2, ylap, sumA, sumY);
    scan_mid<<<dim3(D_ / 256, B_), 256, 0, stream>>>(sumA, sumY, carry);
    scan_apply<<<dim3(4096), 256, 0, stream>>>(carry, ylap, y);
}